// Round 11
// baseline (247.421 us; speedup 1.0000x reference)
//
#include <hip/hip_runtime.h>
#include <math.h>

#define NPTS 4096
#define NB 4
#define NPOINT 204
#define NGROUP (NB * NPOINT) /* 816 */
#define REPBLKS 256
#define UOFF (NB + REPBLKS)  /* uniform blocks start here */
#define REP_H 0.0005f
#define TOTSEL 161
#define POISON 0xAAAAAAAAu   /* ws re-poison pattern; centers are in [0,1) so
                                their bits are < 0x3F800000 -> never POISON */

typedef float v2f __attribute__((ext_vector_type(2)));

struct SmemFPS {
  float4 rec[2][4];   // per-wave winner {maxval, x, y, z}, parity-buffered
  int tags[2][4];     // per-wave iteration tags (s+1) guarding rec freshness
};
struct SmemRep {
  float lists[4][64][5];
};
struct SmemUni {
  float selx[TOTSEL], sely[TOTSEL], selz[TOTSEL];
  float nnv[TOTSEL];
  unsigned long long wsum64[4];
};
union SmemK1 {
  SmemFPS fps;
  SmemRep rep;
  SmemUni uni;
};

__device__ __forceinline__ void insert5(float (&s)[5], float v) {
  if (v < s[4]) {
    if (v < s[3]) {
      s[4] = s[3];
      if (v < s[2]) {
        s[3] = s[2];
        if (v < s[1]) {
          s[2] = s[1];
          if (v < s[0]) { s[1] = s[0]; s[0] = v; }
          else s[1] = v;
        } else s[2] = v;
      } else s[3] = v;
    } else s[4] = v;
  }
}

__device__ __forceinline__ void merge5(float (&a)[5], const float (&bin)[5]) {
  float A[6], Bv[6];
#pragma unroll
  for (int i = 0; i < 5; ++i) { A[i] = a[i]; Bv[i] = bin[i]; }
  A[5] = INFINITY; Bv[5] = INFINITY;
  float r[5];
#pragma unroll
  for (int k = 0; k < 5; ++k) {
    const bool ta = A[0] <= Bv[0];
    r[k] = ta ? A[0] : Bv[0];
#pragma unroll
    for (int i = 0; i < 5; ++i) {
      A[i]  = ta ? A[i + 1] : A[i];
      Bv[i] = ta ? Bv[i] : Bv[i + 1];
    }
  }
#pragma unroll
  for (int i = 0; i < 5; ++i) a[i] = r[i];
}

__device__ __forceinline__ float bcast_lane(float x, int k) {
  return __uint_as_float(__builtin_amdgcn_readlane(__float_as_uint(x), k));
}

// Wave64 max of nonnegative-float bits via DPP; uniform result from lane 63.
__device__ __forceinline__ unsigned wave_max_bits(unsigned x) {
  int v = (int)x;
  v = max((unsigned)v, (unsigned)__builtin_amdgcn_update_dpp(0, v, 0x111, 0xF, 0xF, false)); // row_shr:1
  v = max((unsigned)v, (unsigned)__builtin_amdgcn_update_dpp(0, v, 0x112, 0xF, 0xF, false)); // row_shr:2
  v = max((unsigned)v, (unsigned)__builtin_amdgcn_update_dpp(0, v, 0x114, 0xF, 0xF, false)); // row_shr:4
  v = max((unsigned)v, (unsigned)__builtin_amdgcn_update_dpp(0, v, 0x118, 0xF, 0xF, false)); // row_shr:8
  v = max((unsigned)v, (unsigned)__builtin_amdgcn_update_dpp(0, v, 0x142, 0xF, 0xF, false)); // row_bcast:15
  v = max((unsigned)v, (unsigned)__builtin_amdgcn_update_dpp(0, v, 0x143, 0xF, 0xF, false)); // row_bcast:31
  return (unsigned)__builtin_amdgcn_readlane(v, 63);
}

// One fused kernel (tag-spin exchange: NO s_barrier in the FPS loop):
//  blocks [0..3]      : FPS (producer) - cross-wave exchange via tagged LDS
//                       records (active spin, no sleep/wake); fire-and-forget
//                       agent-scope center publishes.
//  blocks [4..259]    : repulsion (independent).
//  blocks [260..1075] : uniform loss (consumer) - polls ITS OWN center words
//                       against the 0xAA poison sentinel, VALU ballast.
__global__ __launch_bounds__(256) void k1_fused(const float* __restrict__ pcd,
                                                float* __restrict__ centers,
                                                float* __restrict__ uloss,
                                                float* __restrict__ repout) {
  __shared__ SmemK1 sm;
  const int t = threadIdx.x;
  if (blockIdx.x < NB) {
    // ------------------ FPS: 4 waves, 16 pts/lane, packed-fp32 ------------------
    asm volatile("s_setprio 3" ::: "memory");  // out-issue any co-resident waves
    const int b = blockIdx.x;
    const float* __restrict__ P = pcd + (size_t)b * NPTS * 3;
    const float4* __restrict__ P4 = (const float4*)P;
    float* Cb = centers + (size_t)b * NPOINT * 3;
    if (t < 8) ((int*)sm.fps.tags)[t] = 0;  // tags start at 0; first want = 1
    float c[48];
#pragma unroll
    for (int m = 0; m < 12; ++m) {
      const float4 v = P4[t * 12 + m];
      c[4 * m + 0] = v.x; c[4 * m + 1] = v.y; c[4 * m + 2] = v.z; c[4 * m + 3] = v.w;
    }
    v2f px2[8], py2[8], pz2[8], mind2[8];
#pragma unroll
    for (int j = 0; j < 8; ++j) {
      px2[j] = (v2f){c[6 * j + 0], c[6 * j + 3]};
      py2[j] = (v2f){c[6 * j + 1], c[6 * j + 4]};
      pz2[j] = (v2f){c[6 * j + 2], c[6 * j + 5]};
      mind2[j] = (v2f){INFINITY, INFINITY};
    }
    const int lane = t & 63, w = t >> 6;
    float cx = P[0], cy = P[1], cz = P[2];  // start point = index 0
    if (t == 0) {
      __hip_atomic_store(&Cb[0], cx, __ATOMIC_RELAXED, __HIP_MEMORY_SCOPE_AGENT);
      __hip_atomic_store(&Cb[1], cy, __ATOMIC_RELAXED, __HIP_MEMORY_SCOPE_AGENT);
      __hip_atomic_store(&Cb[2], cz, __ATOMIC_RELAXED, __HIP_MEMORY_SCOPE_AGENT);
    }
    __syncthreads();  // once: tags initialized before any wave's first spin
    for (int s = 0; s < NPOINT - 1; ++s) {
      const v2f vcx = (v2f){cx, cx}, vcy = (v2f){cy, cy}, vcz = (v2f){cz, cz};
      unsigned bmax = 0u;
#pragma unroll
      for (int j = 0; j < 8; ++j) {
        const v2f dx = px2[j] - vcx, dy = py2[j] - vcy, dz = pz2[j] - vcz;
        const v2f d = dx * dx + dy * dy + dz * dz;  // v_pk_mul/fma_f32
        const float m0 = fminf(mind2[j].x, d.x);
        const float m1 = fminf(mind2[j].y, d.y);
        mind2[j].x = m0; mind2[j].y = m1;
        bmax = max(bmax, max(__float_as_uint(m0), __float_as_uint(m1)));
      }
      const unsigned wm = wave_max_bits(bmax);  // wave-uniform max (d>=0)
      int li = 16; float wx = 0.f, wy = 0.f, wz = 0.f;
#pragma unroll
      for (int j = 7; j >= 0; --j) {
        if (__float_as_uint(mind2[j].y) == wm) { li = 2 * j + 1; wx = px2[j].y; wy = py2[j].y; wz = pz2[j].y; }
        if (__float_as_uint(mind2[j].x) == wm) { li = 2 * j;     wx = px2[j].x; wy = py2[j].x; wz = pz2[j].x; }
      }
      const unsigned long long mk = __ballot(li < 16);
      const int L = (int)__builtin_ctzll(mk);  // lowest lane with the max
      const float bx = bcast_lane(wx, L);
      const float by = bcast_lane(wy, L);
      const float bz = bcast_lane(wz, L);
      const int par = s & 1;
      const int want = s + 1;
      // Tagged exchange: record first, lgkmcnt-drain, then tag. A parity slot
      // is only overwritten 2 iterations later, which requires every wave to
      // have consumed the old record (induction over the exchange) -> safe.
      if (lane == 0) {
        sm.fps.rec[par][w] = make_float4(__uint_as_float(wm), bx, by, bz);
        asm volatile("s_waitcnt lgkmcnt(0)" ::: "memory");
        *(volatile int*)&sm.fps.tags[par][w] = want;
      }
      {
        volatile int* tg = &sm.fps.tags[par][0];
        int t0, t1, t2, t3;
        do { t0 = tg[0]; t1 = tg[1]; t2 = tg[2]; t3 = tg[3]; }
        while (t0 != want || t1 != want || t2 != want || t3 != want);
        asm volatile("" ::: "memory");  // no hoisting of rec reads above spin
      }
      // all threads pick global winner; strict > keeps lowest wave (== lowest idx)
      float4 best = sm.fps.rec[par][0];
#pragma unroll
      for (int ww = 1; ww < 4; ++ww) {
        const float4 r = sm.fps.rec[par][ww];
        if (r.x > best.x) best = r;
      }
      cx = best.y; cy = best.z; cz = best.w;
      // fire-and-forget publish; consumers snoop these words vs the poison
      // sentinel. No flag, no waits -> producer loop never touches vmcnt.
      if (t == 0) {
        float* cp = Cb + 3 * (s + 1);
        __hip_atomic_store(&cp[0], cx, __ATOMIC_RELAXED, __HIP_MEMORY_SCOPE_AGENT);
        __hip_atomic_store(&cp[1], cy, __ATOMIC_RELAXED, __HIP_MEMORY_SCOPE_AGENT);
        __hip_atomic_store(&cp[2], cz, __ATOMIC_RELAXED, __HIP_MEMORY_SCOPE_AGENT);
      }
    }
  } else if (blockIdx.x < UOFF) {
    // ------------------ repulsion ------------------
    const int rblk = blockIdx.x - NB;       // 0..255
    const int b = rblk >> 6;                // batch
    const int qbase = (rblk & 63) * 64;     // 64 queries per block
    const float* __restrict__ P = pcd + (size_t)b * NPTS * 3;
    const int lane = t & 63;
    const int w = t >> 6;                   // wave = candidate subset (4 x 1024)
    const int q = qbase + lane;
    const float qx = P[3 * q + 0], qy = P[3 * q + 1], qz = P[3 * q + 2];
    float s5[5];
#pragma unroll
    for (int i = 0; i < 5; ++i) s5[i] = INFINITY;
    for (int c = 0; c < 16; ++c) {
      const int ci = (w << 10) + (c << 6) + lane;
      const float ox = P[3 * ci + 0], oy = P[3 * ci + 1], oz = P[3 * ci + 2];
#pragma unroll
      for (int k = 0; k < 64; ++k) {
        const float cxv = bcast_lane(ox, k);
        const float cyv = bcast_lane(oy, k);
        const float czv = bcast_lane(oz, k);
        const float dx = qx - cxv, dy = qy - cyv, dz = qz - czv;
        const float d2 = dx * dx + dy * dy + dz * dz;
        insert5(s5, d2);
      }
    }
#pragma unroll
    for (int i = 0; i < 5; ++i) sm.rep.lists[w][lane][i] = s5[i];
    __syncthreads();
    float tsum = 0.0f;
    if (w == 0) {
#pragma unroll
      for (int pw = 1; pw < 4; ++pw) {
        float bin[5];
#pragma unroll
        for (int i = 0; i < 5; ++i) bin[i] = sm.rep.lists[pw][lane][i];
        merge5(s5, bin);
      }
#pragma unroll
      for (int i = 1; i < 5; ++i) tsum += fmaxf(REP_H - s5[i] * s5[i], 0.0f);
    }
#pragma unroll
    for (int off = 32; off > 0; off >>= 1) tsum += __shfl_xor(tsum, off);
    if (t == 0) repout[rblk] = tsum;
  } else {
    // ------------------ uniform loss (consumer) ------------------
    const int g = blockIdx.x - UOFF;  // 0..815
    const int b = g / NPOINT;
    const float* __restrict__ P = pcd + (size_t)b * NPTS * 3;
    const float4* __restrict__ P4 = (const float4*)P;
    float c[48];
#pragma unroll
    for (int m = 0; m < 12; ++m) {
      const float4 v = P4[t * 12 + m];
      c[4 * m + 0] = v.x; c[4 * m + 1] = v.y; c[4 * m + 2] = v.z; c[4 * m + 3] = v.w;
    }
    // Snoop this block's own center words against the poison sentinel.
    // centers are copies of pcd points in [0,1): bits < 0x3F800000, so
    // 0xAAAAAAAA can never be a legit value. Each block polls its own 12 B
    // (816 spread addresses -> no hot line). Ballast keeps clocks up.
    float cxx, cyy, czz;
    {
      const unsigned* cp = (const unsigned*)(centers + (size_t)g * 3);
      float z0 = 1.0f;
      const float z1 = 1.000001f;
      unsigned w0, w1, w2;
      for (;;) {
        w0 = __hip_atomic_load(&cp[0], __ATOMIC_RELAXED, __HIP_MEMORY_SCOPE_AGENT);
        w1 = __hip_atomic_load(&cp[1], __ATOMIC_RELAXED, __HIP_MEMORY_SCOPE_AGENT);
        w2 = __hip_atomic_load(&cp[2], __ATOMIC_RELAXED, __HIP_MEMORY_SCOPE_AGENT);
        if (w0 != POISON && w1 != POISON && w2 != POISON) break;
#pragma unroll
        for (int i = 0; i < 128; ++i)
          asm volatile("v_fmac_f32 %0, %1, %1" : "+v"(z0) : "v"(z1));
      }
      cxx = __uint_as_float(w0); cyy = __uint_as_float(w1); czz = __uint_as_float(w2);
    }
    const float ca2 = cxx * cxx + cyy * cyy + czz * czz;
    float d2r[16];
#pragma unroll
    for (int k = 0; k < 16; ++k) {
      const float x = c[3 * k], y = c[3 * k + 1], z = c[3 * k + 2];
      const float b2 = x * x + y * y + z * z;
      const float dt = cxx * x + cyy * y + czz * z;
      d2r[k] = fmaxf(ca2 + b2 - 2.0f * dt, 0.0f);  // same clamped formula as reference
    }
    const int KK[5] = {16, 24, 32, 40, 49};
    const int OFF[5] = {0, 16, 40, 72, 112};
    const float EXPECT = (float)sqrt(M_PI / 4096.0);
    const int lane = t & 63, wv = t >> 6;
    const double pv[5] = {0.004, 0.006, 0.008, 0.01, 0.012};
    unsigned msk[5];
    unsigned long long cnt64 = 0ull;
#pragma unroll
    for (int p = 0; p < 5; ++p) {
      const double rd = sqrt(pv[p]);
      const float rr = (float)(rd * rd);
      unsigned m = 0;
#pragma unroll
      for (int k = 0; k < 16; ++k)
        if (d2r[k] < rr) m |= (1u << k);
      msk[p] = m;
      cnt64 |= (unsigned long long)__popc(m) << (12 * p);
    }
    // inclusive scan across the wave (field totals < 4096 -> no cross-field carry)
    unsigned long long incl = cnt64;
#pragma unroll
    for (int off = 1; off < 64; off <<= 1) {
      const unsigned long long nv = __shfl_up(incl, off);
      if (lane >= off) incl += nv;
    }
    if (lane == 63) sm.uni.wsum64[wv] = incl;
    __syncthreads();
    unsigned long long prefix = 0ull, total64 = 0ull;
#pragma unroll
    for (int ww = 0; ww < 4; ++ww) {
      const unsigned long long v = sm.uni.wsum64[ww];
      if (ww < wv) prefix += v;
      total64 += v;
    }
    const unsigned long long excl = incl - cnt64;
    // compaction: first-K (ascending global index) per percentage
#pragma unroll
    for (int p = 0; p < 5; ++p) {
      int pos = (int)((excl >> (12 * p)) & 0xFFF) + (int)((prefix >> (12 * p)) & 0xFFF);
      const unsigned m = msk[p];
      const int K = KK[p], off = OFF[p];
#pragma unroll
      for (int k = 0; k < 16; ++k) {
        if (m & (1u << k)) {
          if (pos < K) {
            sm.uni.selx[off + pos] = c[3 * k];
            sm.uni.sely[off + pos] = c[3 * k + 1];
            sm.uni.selz[off + pos] = c[3 * k + 2];
          }
          ++pos;
        }
      }
    }
    // zero-pad tails (disjoint from compaction writes)
    if (t < TOTSEL) {
      int p, off;
      if (t < 16) { p = 0; off = 0; }
      else if (t < 40) { p = 1; off = 16; }
      else if (t < 72) { p = 2; off = 40; }
      else if (t < 112) { p = 3; off = 72; }
      else { p = 4; off = 112; }
      const int j = t - off;
      const int tot = (int)((total64 >> (12 * p)) & 0xFFF);
      const int realc = tot < KK[p] ? tot : KK[p];
      if (j >= realc) { sm.uni.selx[t] = 0.0f; sm.uni.sely[t] = 0.0f; sm.uni.selz[t] = 0.0f; }
    }
    __syncthreads();
    // NN rows for all 5 groups concurrently
    if (t < TOTSEL) {
      int p, off;
      if (t < 16) { p = 0; off = 0; }
      else if (t < 40) { p = 1; off = 16; }
      else if (t < 72) { p = 2; off = 40; }
      else if (t < 112) { p = 3; off = 72; }
      else { p = 4; off = 112; }
      const int j = t - off;
      const int K = KK[p];
      const float xi = sm.uni.selx[t], yi = sm.uni.sely[t], zi = sm.uni.selz[t];
      const float ai = xi * xi + yi * yi + zi * zi;
      float m = INFINITY;
      for (int jj = 0; jj < K; ++jj) {
        if (jj == j) continue;
        const float xj = sm.uni.selx[off + jj], yj = sm.uni.sely[off + jj], zj = sm.uni.selz[off + jj];
        const float aj = xj * xj + yj * yj + zj * zj;
        float d = ai + aj - 2.0f * (xi * xj + yi * yj + zi * zj);
        d = fmaxf(d, 0.0f);
        m = fminf(m, d);
      }
      sm.uni.nnv[t] = m + 1e-8f;
    }
    __syncthreads();
    // 5 lead threads reduce their group in parallel
    if (t == 0 || t == 16 || t == 40 || t == 72 || t == 112) {
      int p;
      if (t == 0) p = 0; else if (t == 16) p = 1; else if (t == 40) p = 2;
      else if (t == 72) p = 3; else p = 4;
      const int K = KK[p];
      double ssum = 0.0;
      for (int j = 0; j < K; ++j) ssum += (double)sm.uni.nnv[t + j];
      const float u = (float)(ssum / (double)K);
      const float df = u - EXPECT;
      uloss[p * NGROUP + g] = df * df / (EXPECT + 1e-8f);
    }
  }
}

__global__ __launch_bounds__(256) void k3_reduce(const float* __restrict__ uloss,
                                                 const float* __restrict__ repout,
                                                 float* __restrict__ out) {
  __shared__ double sd[256];
  const int t = threadIdx.x;
  const double wl[5] = {0.16, 0.36, 0.64, 1.0, 1.44};  // (p*100)^2
  double acc = 0.0;
#pragma unroll
  for (int p = 0; p < 5; ++p) {
    double a2 = 0.0;
    for (int i = t; i < NGROUP; i += 256) a2 += (double)uloss[p * NGROUP + i];
    acc += wl[p] * a2;
  }
  acc *= (1.0 / ((double)NGROUP * 5.0));
  acc += (double)repout[t] * (1.0 / 65536.0);  // mean over (B,N,4) = 4*4096*4
  sd[t] = acc;
  __syncthreads();
  for (int s = 128; s > 0; s >>= 1) {
    if (t < s) sd[t] += sd[t + s];
    __syncthreads();
  }
  if (t == 0) out[0] = (float)sd[0];
}

extern "C" void kernel_launch(void* const* d_in, const int* in_sizes, int n_in,
                              void* d_out, int out_size, void* d_ws, size_t ws_size,
                              hipStream_t stream) {
  const float* pcd = (const float*)d_in[0];
  float* out = (float*)d_out;
  float* centers = (float*)d_ws;              // 4*204*3 = 2448 floats
  float* uloss = centers + NB * NPOINT * 3;   // 5*816 = 4080 floats
  float* repout = uloss + 5 * NGROUP;         // 256 floats
  k1_fused<<<UOFF + NGROUP, 256, 0, stream>>>(pcd, centers, uloss, repout);
  k3_reduce<<<1, 256, 0, stream>>>(uloss, repout, out);
}

// Round 12
// 206.771 us; speedup vs baseline: 1.1966x; 1.1966x over previous
//
#include <hip/hip_runtime.h>
#include <math.h>

#define NPTS 4096
#define NB 4
#define NPOINT 204
#define NGROUP (NB * NPOINT) /* 816 */
#define REPBLKS 256
#define UOFF (NB + REPBLKS)  /* uniform blocks start here */
#define REP_H 0.0005f
#define TOTSEL 161
#define POISON 0xAAAAAAAAu   /* ws re-poison pattern; centers are in [0,1) so
                                their bits are < 0x3F800000 -> never POISON */

typedef float v2f __attribute__((ext_vector_type(2)));

struct SmemFPS {
  float4 wrec[2][4];  // per-wave winner {maxval, x, y, z}, parity-buffered
};
struct SmemRep {
  float lists[4][64][5];
};
struct SmemUni {
  float selx[TOTSEL], sely[TOTSEL], selz[TOTSEL];
  float nnv[TOTSEL];
  unsigned long long wsum64[4];
};
union SmemK1 {
  SmemFPS fps;
  SmemRep rep;
  SmemUni uni;
};

__device__ __forceinline__ void insert5(float (&s)[5], float v) {
  if (v < s[4]) {
    if (v < s[3]) {
      s[4] = s[3];
      if (v < s[2]) {
        s[3] = s[2];
        if (v < s[1]) {
          s[2] = s[1];
          if (v < s[0]) { s[1] = s[0]; s[0] = v; }
          else s[1] = v;
        } else s[2] = v;
      } else s[3] = v;
    } else s[4] = v;
  }
}

__device__ __forceinline__ void merge5(float (&a)[5], const float (&bin)[5]) {
  float A[6], Bv[6];
#pragma unroll
  for (int i = 0; i < 5; ++i) { A[i] = a[i]; Bv[i] = bin[i]; }
  A[5] = INFINITY; Bv[5] = INFINITY;
  float r[5];
#pragma unroll
  for (int k = 0; k < 5; ++k) {
    const bool ta = A[0] <= Bv[0];
    r[k] = ta ? A[0] : Bv[0];
#pragma unroll
    for (int i = 0; i < 5; ++i) {
      A[i]  = ta ? A[i + 1] : A[i];
      Bv[i] = ta ? Bv[i] : Bv[i + 1];
    }
  }
#pragma unroll
  for (int i = 0; i < 5; ++i) a[i] = r[i];
}

__device__ __forceinline__ float bcast_lane(float x, int k) {
  return __uint_as_float(__builtin_amdgcn_readlane(__float_as_uint(x), k));
}

// Wave64 max of nonnegative-float bits via DPP; uniform result from lane 63.
__device__ __forceinline__ unsigned wave_max_bits(unsigned x) {
  int v = (int)x;
  v = max((unsigned)v, (unsigned)__builtin_amdgcn_update_dpp(0, v, 0x111, 0xF, 0xF, false)); // row_shr:1
  v = max((unsigned)v, (unsigned)__builtin_amdgcn_update_dpp(0, v, 0x112, 0xF, 0xF, false)); // row_shr:2
  v = max((unsigned)v, (unsigned)__builtin_amdgcn_update_dpp(0, v, 0x114, 0xF, 0xF, false)); // row_shr:4
  v = max((unsigned)v, (unsigned)__builtin_amdgcn_update_dpp(0, v, 0x118, 0xF, 0xF, false)); // row_shr:8
  v = max((unsigned)v, (unsigned)__builtin_amdgcn_update_dpp(0, v, 0x142, 0xF, 0xF, false)); // row_bcast:15
  v = max((unsigned)v, (unsigned)__builtin_amdgcn_update_dpp(0, v, 0x143, 0xF, 0xF, false)); // row_bcast:31
  return (unsigned)__builtin_amdgcn_readlane(v, 63);
}

// One fused kernel (sentinel-snoop protocol, s_barrier exchange):
//  blocks [0..3]      : FPS (producer) - fire-and-forget agent-scope center
//                       stores; tree-split rescan to halve the serial chain.
//  blocks [4..259]    : repulsion (independent).
//  blocks [260..1075] : uniform loss (consumer) - s_sleep snoop on ITS OWN
//                       center words vs the 0xAA poison sentinel (low power
//                       -> leaves thermal/power headroom for the FPS clock).
__global__ __launch_bounds__(256) void k1_fused(const float* __restrict__ pcd,
                                                float* __restrict__ centers,
                                                float* __restrict__ uloss,
                                                float* __restrict__ repout) {
  __shared__ SmemK1 sm;
  const int t = threadIdx.x;
  if (blockIdx.x < NB) {
    // ------------------ FPS: 4 waves, 16 pts/lane, packed-fp32 ------------------
    asm volatile("s_setprio 3" ::: "memory");  // out-issue any co-resident waves
    const int b = blockIdx.x;
    const float* __restrict__ P = pcd + (size_t)b * NPTS * 3;
    const float4* __restrict__ P4 = (const float4*)P;
    float* Cb = centers + (size_t)b * NPOINT * 3;
    float c[48];
#pragma unroll
    for (int m = 0; m < 12; ++m) {
      const float4 v = P4[t * 12 + m];
      c[4 * m + 0] = v.x; c[4 * m + 1] = v.y; c[4 * m + 2] = v.z; c[4 * m + 3] = v.w;
    }
    v2f px2[8], py2[8], pz2[8], mind2[8];
#pragma unroll
    for (int j = 0; j < 8; ++j) {
      px2[j] = (v2f){c[6 * j + 0], c[6 * j + 3]};
      py2[j] = (v2f){c[6 * j + 1], c[6 * j + 4]};
      pz2[j] = (v2f){c[6 * j + 2], c[6 * j + 5]};
      mind2[j] = (v2f){INFINITY, INFINITY};
    }
    const int lane = t & 63, w = t >> 6;
    float cx = P[0], cy = P[1], cz = P[2];  // start point = index 0
    if (t == 0) {
      __hip_atomic_store(&Cb[0], cx, __ATOMIC_RELAXED, __HIP_MEMORY_SCOPE_AGENT);
      __hip_atomic_store(&Cb[1], cy, __ATOMIC_RELAXED, __HIP_MEMORY_SCOPE_AGENT);
      __hip_atomic_store(&Cb[2], cz, __ATOMIC_RELAXED, __HIP_MEMORY_SCOPE_AGENT);
    }
    for (int s = 0; s < NPOINT - 1; ++s) {
      const v2f vcx = (v2f){cx, cx}, vcy = (v2f){cy, cy}, vcz = (v2f){cz, cz};
      // dual accumulation chains halve the serial bmax latency
      unsigned bmaxA = 0u, bmaxB = 0u;
#pragma unroll
      for (int j = 0; j < 8; ++j) {
        const v2f dx = px2[j] - vcx, dy = py2[j] - vcy, dz = pz2[j] - vcz;
        const v2f d = dx * dx + dy * dy + dz * dz;  // v_pk_mul/fma_f32
        const float m0 = fminf(mind2[j].x, d.x);
        const float m1 = fminf(mind2[j].y, d.y);
        mind2[j].x = m0; mind2[j].y = m1;
        if (j & 1) bmaxB = max(bmaxB, max(__float_as_uint(m0), __float_as_uint(m1)));
        else       bmaxA = max(bmaxA, max(__float_as_uint(m0), __float_as_uint(m1)));
      }
      const unsigned bmax = max(bmaxA, bmaxB);
      const unsigned wm = wave_max_bits(bmax);  // wave-uniform max (d>=0)
      // tree-split rescan: two independent 8-pt chains, merged with
      // half-A (k 0..7) preferred on equal value -> exact lowest-k tie-break
      int liA = 16, liB = 16;
      float axx = 0.f, ayy = 0.f, azz = 0.f, bxx = 0.f, byy = 0.f, bzz = 0.f;
#pragma unroll
      for (int j = 3; j >= 0; --j) {
        if (__float_as_uint(mind2[j].y) == wm) { liA = 2 * j + 1; axx = px2[j].y; ayy = py2[j].y; azz = pz2[j].y; }
        if (__float_as_uint(mind2[j].x) == wm) { liA = 2 * j;     axx = px2[j].x; ayy = py2[j].x; azz = pz2[j].x; }
      }
#pragma unroll
      for (int j = 7; j >= 4; --j) {
        if (__float_as_uint(mind2[j].y) == wm) { liB = 2 * j + 1; bxx = px2[j].y; byy = py2[j].y; bzz = pz2[j].y; }
        if (__float_as_uint(mind2[j].x) == wm) { liB = 2 * j;     bxx = px2[j].x; byy = py2[j].x; bzz = pz2[j].x; }
      }
      const bool useA = liA < 16;
      const int li = useA ? liA : liB;
      const float wx = useA ? axx : bxx;
      const float wy = useA ? ayy : byy;
      const float wz = useA ? azz : bzz;
      const unsigned long long mk = __ballot(li < 16);
      const int L = (int)__builtin_ctzll(mk);  // lowest lane with the max
      const float bx = bcast_lane(wx, L);
      const float by = bcast_lane(wy, L);
      const float bz = bcast_lane(wz, L);
      const int par = s & 1;
      if (lane == 0) sm.fps.wrec[par][w] = make_float4(__uint_as_float(wm), bx, by, bz);
      __syncthreads();
      // all threads pick global winner; strict > keeps lowest wave (== lowest idx)
      float4 best = sm.fps.wrec[par][0];
#pragma unroll
      for (int ww = 1; ww < 4; ++ww) {
        const float4 r = sm.fps.wrec[par][ww];
        if (r.x > best.x) best = r;
      }
      cx = best.y; cy = best.z; cz = best.w;
      // fire-and-forget publish; consumers snoop these words vs the poison
      // sentinel. No flag, no waits -> producer loop never touches vmcnt.
      if (t == 0) {
        float* cp = Cb + 3 * (s + 1);
        __hip_atomic_store(&cp[0], cx, __ATOMIC_RELAXED, __HIP_MEMORY_SCOPE_AGENT);
        __hip_atomic_store(&cp[1], cy, __ATOMIC_RELAXED, __HIP_MEMORY_SCOPE_AGENT);
        __hip_atomic_store(&cp[2], cz, __ATOMIC_RELAXED, __HIP_MEMORY_SCOPE_AGENT);
      }
    }
  } else if (blockIdx.x < UOFF) {
    // ------------------ repulsion ------------------
    const int rblk = blockIdx.x - NB;       // 0..255
    const int b = rblk >> 6;                // batch
    const int qbase = (rblk & 63) * 64;     // 64 queries per block
    const float* __restrict__ P = pcd + (size_t)b * NPTS * 3;
    const int lane = t & 63;
    const int w = t >> 6;                   // wave = candidate subset (4 x 1024)
    const int q = qbase + lane;
    const float qx = P[3 * q + 0], qy = P[3 * q + 1], qz = P[3 * q + 2];
    float s5[5];
#pragma unroll
    for (int i = 0; i < 5; ++i) s5[i] = INFINITY;
    for (int c = 0; c < 16; ++c) {
      const int ci = (w << 10) + (c << 6) + lane;
      const float ox = P[3 * ci + 0], oy = P[3 * ci + 1], oz = P[3 * ci + 2];
#pragma unroll
      for (int k = 0; k < 64; ++k) {
        const float cxv = bcast_lane(ox, k);
        const float cyv = bcast_lane(oy, k);
        const float czv = bcast_lane(oz, k);
        const float dx = qx - cxv, dy = qy - cyv, dz = qz - czv;
        const float d2 = dx * dx + dy * dy + dz * dz;
        insert5(s5, d2);
      }
    }
#pragma unroll
    for (int i = 0; i < 5; ++i) sm.rep.lists[w][lane][i] = s5[i];
    __syncthreads();
    float tsum = 0.0f;
    if (w == 0) {
#pragma unroll
      for (int pw = 1; pw < 4; ++pw) {
        float bin[5];
#pragma unroll
        for (int i = 0; i < 5; ++i) bin[i] = sm.rep.lists[pw][lane][i];
        merge5(s5, bin);
      }
#pragma unroll
      for (int i = 1; i < 5; ++i) tsum += fmaxf(REP_H - s5[i] * s5[i], 0.0f);
    }
#pragma unroll
    for (int off = 32; off > 0; off >>= 1) tsum += __shfl_xor(tsum, off);
    if (t == 0) repout[rblk] = tsum;
  } else {
    // ------------------ uniform loss (consumer) ------------------
    const int g = blockIdx.x - UOFF;  // 0..815
    const int b = g / NPOINT;
    const float* __restrict__ P = pcd + (size_t)b * NPTS * 3;
    const float4* __restrict__ P4 = (const float4*)P;
    float c[48];
#pragma unroll
    for (int m = 0; m < 12; ++m) {
      const float4 v = P4[t * 12 + m];
      c[4 * m + 0] = v.x; c[4 * m + 1] = v.y; c[4 * m + 2] = v.z; c[4 * m + 3] = v.w;
    }
    // Snoop this block's own center words against the poison sentinel.
    // centers are copies of pcd points in [0,1): bits < 0x3F800000, so
    // 0xAAAAAAAA can never be a legit value. Each block polls its own 12 B
    // (816 spread addresses -> no hot line). s_sleep keeps power low ->
    // thermal/power headroom for the serial FPS waves' clock.
    float cxx, cyy, czz;
    {
      const unsigned* cp = (const unsigned*)(centers + (size_t)g * 3);
      unsigned w0, w1, w2;
      for (;;) {
        w0 = __hip_atomic_load(&cp[0], __ATOMIC_RELAXED, __HIP_MEMORY_SCOPE_AGENT);
        w1 = __hip_atomic_load(&cp[1], __ATOMIC_RELAXED, __HIP_MEMORY_SCOPE_AGENT);
        w2 = __hip_atomic_load(&cp[2], __ATOMIC_RELAXED, __HIP_MEMORY_SCOPE_AGENT);
        if (w0 != POISON && w1 != POISON && w2 != POISON) break;
        __builtin_amdgcn_s_sleep(2);
      }
      cxx = __uint_as_float(w0); cyy = __uint_as_float(w1); czz = __uint_as_float(w2);
    }
    const float ca2 = cxx * cxx + cyy * cyy + czz * czz;
    float d2r[16];
#pragma unroll
    for (int k = 0; k < 16; ++k) {
      const float x = c[3 * k], y = c[3 * k + 1], z = c[3 * k + 2];
      const float b2 = x * x + y * y + z * z;
      const float dt = cxx * x + cyy * y + czz * z;
      d2r[k] = fmaxf(ca2 + b2 - 2.0f * dt, 0.0f);  // same clamped formula as reference
    }
    const int KK[5] = {16, 24, 32, 40, 49};
    const int OFF[5] = {0, 16, 40, 72, 112};
    const float EXPECT = (float)sqrt(M_PI / 4096.0);
    const int lane = t & 63, wv = t >> 6;
    const double pv[5] = {0.004, 0.006, 0.008, 0.01, 0.012};
    unsigned msk[5];
    unsigned long long cnt64 = 0ull;
#pragma unroll
    for (int p = 0; p < 5; ++p) {
      const double rd = sqrt(pv[p]);
      const float rr = (float)(rd * rd);
      unsigned m = 0;
#pragma unroll
      for (int k = 0; k < 16; ++k)
        if (d2r[k] < rr) m |= (1u << k);
      msk[p] = m;
      cnt64 |= (unsigned long long)__popc(m) << (12 * p);
    }
    // inclusive scan across the wave (field totals < 4096 -> no cross-field carry)
    unsigned long long incl = cnt64;
#pragma unroll
    for (int off = 1; off < 64; off <<= 1) {
      const unsigned long long nv = __shfl_up(incl, off);
      if (lane >= off) incl += nv;
    }
    if (lane == 63) sm.uni.wsum64[wv] = incl;
    __syncthreads();
    unsigned long long prefix = 0ull, total64 = 0ull;
#pragma unroll
    for (int ww = 0; ww < 4; ++ww) {
      const unsigned long long v = sm.uni.wsum64[ww];
      if (ww < wv) prefix += v;
      total64 += v;
    }
    const unsigned long long excl = incl - cnt64;
    // compaction: first-K (ascending global index) per percentage
#pragma unroll
    for (int p = 0; p < 5; ++p) {
      int pos = (int)((excl >> (12 * p)) & 0xFFF) + (int)((prefix >> (12 * p)) & 0xFFF);
      const unsigned m = msk[p];
      const int K = KK[p], off = OFF[p];
#pragma unroll
      for (int k = 0; k < 16; ++k) {
        if (m & (1u << k)) {
          if (pos < K) {
            sm.uni.selx[off + pos] = c[3 * k];
            sm.uni.sely[off + pos] = c[3 * k + 1];
            sm.uni.selz[off + pos] = c[3 * k + 2];
          }
          ++pos;
        }
      }
    }
    // zero-pad tails (disjoint from compaction writes)
    if (t < TOTSEL) {
      int p, off;
      if (t < 16) { p = 0; off = 0; }
      else if (t < 40) { p = 1; off = 16; }
      else if (t < 72) { p = 2; off = 40; }
      else if (t < 112) { p = 3; off = 72; }
      else { p = 4; off = 112; }
      const int j = t - off;
      const int tot = (int)((total64 >> (12 * p)) & 0xFFF);
      const int realc = tot < KK[p] ? tot : KK[p];
      if (j >= realc) { sm.uni.selx[t] = 0.0f; sm.uni.sely[t] = 0.0f; sm.uni.selz[t] = 0.0f; }
    }
    __syncthreads();
    // NN rows for all 5 groups concurrently
    if (t < TOTSEL) {
      int p, off;
      if (t < 16) { p = 0; off = 0; }
      else if (t < 40) { p = 1; off = 16; }
      else if (t < 72) { p = 2; off = 40; }
      else if (t < 112) { p = 3; off = 72; }
      else { p = 4; off = 112; }
      const int j = t - off;
      const int K = KK[p];
      const float xi = sm.uni.selx[t], yi = sm.uni.sely[t], zi = sm.uni.selz[t];
      const float ai = xi * xi + yi * yi + zi * zi;
      float m = INFINITY;
      for (int jj = 0; jj < K; ++jj) {
        if (jj == j) continue;
        const float xj = sm.uni.selx[off + jj], yj = sm.uni.sely[off + jj], zj = sm.uni.selz[off + jj];
        const float aj = xj * xj + yj * yj + zj * zj;
        float d = ai + aj - 2.0f * (xi * xj + yi * yj + zi * zj);
        d = fmaxf(d, 0.0f);
        m = fminf(m, d);
      }
      sm.uni.nnv[t] = m + 1e-8f;
    }
    __syncthreads();
    // 5 lead threads reduce their group in parallel
    if (t == 0 || t == 16 || t == 40 || t == 72 || t == 112) {
      int p;
      if (t == 0) p = 0; else if (t == 16) p = 1; else if (t == 40) p = 2;
      else if (t == 72) p = 3; else p = 4;
      const int K = KK[p];
      double ssum = 0.0;
      for (int j = 0; j < K; ++j) ssum += (double)sm.uni.nnv[t + j];
      const float u = (float)(ssum / (double)K);
      const float df = u - EXPECT;
      uloss[p * NGROUP + g] = df * df / (EXPECT + 1e-8f);
    }
  }
}

__global__ __launch_bounds__(256) void k3_reduce(const float* __restrict__ uloss,
                                                 const float* __restrict__ repout,
                                                 float* __restrict__ out) {
  __shared__ double sd[256];
  const int t = threadIdx.x;
  const double wl[5] = {0.16, 0.36, 0.64, 1.0, 1.44};  // (p*100)^2
  double acc = 0.0;
#pragma unroll
  for (int p = 0; p < 5; ++p) {
    double a2 = 0.0;
    for (int i = t; i < NGROUP; i += 256) a2 += (double)uloss[p * NGROUP + i];
    acc += wl[p] * a2;
  }
  acc *= (1.0 / ((double)NGROUP * 5.0));
  acc += (double)repout[t] * (1.0 / 65536.0);  // mean over (B,N,4) = 4*4096*4
  sd[t] = acc;
  __syncthreads();
  for (int s = 128; s > 0; s >>= 1) {
    if (t < s) sd[t] += sd[t + s];
    __syncthreads();
  }
  if (t == 0) out[0] = (float)sd[0];
}

extern "C" void kernel_launch(void* const* d_in, const int* in_sizes, int n_in,
                              void* d_out, int out_size, void* d_ws, size_t ws_size,
                              hipStream_t stream) {
  const float* pcd = (const float*)d_in[0];
  float* out = (float*)d_out;
  float* centers = (float*)d_ws;              // 4*204*3 = 2448 floats
  float* uloss = centers + NB * NPOINT * 3;   // 5*816 = 4080 floats
  float* repout = uloss + 5 * NGROUP;         // 256 floats
  k1_fused<<<UOFF + NGROUP, 256, 0, stream>>>(pcd, centers, uloss, repout);
  k3_reduce<<<1, 256, 0, stream>>>(uloss, repout, out);
}